// Round 6
// baseline (540.981 us; speedup 1.0000x reference)
//
#include <hip/hip_runtime.h>
#include <hip/hip_cooperative_groups.h>
#include <math.h>

namespace cg = cooperative_groups;

// Primary path: ONE cooperative launch (mega), phases separated by grid.sync():
//   P0: block 0 zeroes tcnt + bucket_count
//   P1: classify (all blocks, grid-stride, wave-aggregated atomics)
//   P2: block-range split (preserves R1-proven scatter||proj overlap):
//       blocks [0,nscat): bucket scatter (4 edges/thread int4, LDS hist ->
//         slab alloc, one atomicAdd per (block,bucket); R2 lesson: latency-
//         bound, maximize blocks+ILP)
//       blocks [nscat,gsz): proj GEMM z[list[i]] = A[list[i]] @ W
//         (proven TM=128 tile, remapped to 512 thr / 4 rows per thread)
//   P3: attention = R5-proven kernel body, grid-strided over 32-dst buckets
// R4 failure diagnosed as cooperative launch rejected (grid=512 requested with
// zero margin, rc unchecked, output stayed zero). Fix: occupancy-query-driven
// grid, rc checked, R5-proven 4-dispatch pipeline as fallback (a failed coop
// call enqueues nothing, so capture stays valid).
// Assumes N <= 65536 (src packed into low 16 bits of bdata; NBUK <= 2048).

#define F 64
#define TM 128
#define TK 64
#define BSH 5                    // bucket = dst >> 5 (32 dsts per bucket)
#define CHUNK 4096               // edges per scatter task (mult of 4)
#define CAP 1280                 // slab capacity per bucket (mean 800, +17 sigma)
#define HCAP 1280                // per-bucket LDS list capacity
#define BLK 512                  // mega block size
#define SMEM_SZ 49664            // dynamic LDS: proj tile 128*65*4 + 64*64*4

#define PROJ_LDS (128 * (TK + 1) * 4 + TK * F * 4)   // fallback static union

// ---------------------------------------------------------------------------
// mega (cooperative) kernel
// ---------------------------------------------------------------------------
__global__ __launch_bounds__(BLK, 4)
void mega(const float* __restrict__ d_sim, const float* __restrict__ m_sim,
          const float* __restrict__ W_d, const float* __restrict__ W_m,
          const int* __restrict__ node_type, const int* __restrict__ src,
          const int* __restrict__ dst, float* __restrict__ out,
          int* __restrict__ tcnt, int* __restrict__ bcount,
          int* __restrict__ list0, int* __restrict__ list1,
          float* __restrict__ z, int* __restrict__ bdata,
          int n, int ne, int nbuk, int nchunk, int nscat) {
    extern __shared__ __align__(16) char smem[];
    cg::grid_group gg = cg::this_grid();
    const int tid = threadIdx.x;
    const int bid = blockIdx.x;
    const int gsz = gridDim.x;

    // ---------------- P0: zero counters ----------------
    if (bid == 0) {
        for (int i = tid; i < 2050; i += BLK) {
            if (i < 2048) bcount[i] = 0;
            else          tcnt[i - 2048] = 0;
        }
    }
    __threadfence();
    gg.sync();

    // ---------------- P1: classify ----------------
    for (int base = bid * BLK; base < n; base += gsz * BLK) {
        int i = base + tid;
        if (i < n) {
            int lane = tid & 63;
            int t = node_type[i];
            unsigned long long b1 = __ballot(t == 1);
            unsigned long long ba = __ballot(1);
            unsigned long long mlt = (1ull << lane) - 1ull;
            int r1 = __popcll(b1 & mlt);
            int r0 = __popcll(ba & ~b1 & mlt);
            int base0, base1;
            if (lane == 0) {
                base1 = atomicAdd(&tcnt[1], __popcll(b1));
                base0 = atomicAdd(&tcnt[0], __popcll(ba & ~b1));
            }
            base0 = __shfl(base0, 0, 64);
            base1 = __shfl(base1, 0, 64);
            if (t == 1) list1[base1 + r1] = i;
            else        list0[base0 + r0] = i;
        }
    }
    __threadfence();
    gg.sync();

    // ---------------- P2: scatter (blocks < nscat)  ||  proj (rest) ----------------
    if (bid < nscat) {
        int* hist  = (int*)smem;        // [2048]
        int* bbase = hist + 2048;       // [2048]
        int* rk    = bbase + 2048;      // [2048]
        for (int c = bid; c < nchunk; c += nscat) {
            for (int i = tid; i < nbuk; i += BLK) { hist[i] = 0; rk[i] = 0; }
            __syncthreads();
            int beg = c * CHUNK, end = min(ne, beg + CHUNK);
            for (int i = beg + tid * 4; i < end; i += BLK * 4) {
                int4 d4 = *(const int4*)(dst + i);       // e mult of 4 assumed
                atomicAdd(&hist[d4.x >> BSH], 1);
                atomicAdd(&hist[d4.y >> BSH], 1);
                atomicAdd(&hist[d4.z >> BSH], 1);
                atomicAdd(&hist[d4.w >> BSH], 1);
            }
            __syncthreads();
            for (int i = tid; i < nbuk; i += BLK)
                bbase[i] = hist[i] ? atomicAdd(&bcount[i], hist[i]) : 0;
            __syncthreads();
            for (int i = beg + tid * 4; i < end; i += BLK * 4) {
                int4 d4 = *(const int4*)(dst + i);
                int4 s4 = *(const int4*)(src + i);
                int b0 = d4.x >> BSH, b1 = d4.y >> BSH, b2 = d4.z >> BSH, b3 = d4.w >> BSH;
                int r0 = atomicAdd(&rk[b0], 1);
                int r1 = atomicAdd(&rk[b1], 1);
                int r2 = atomicAdd(&rk[b2], 1);
                int r3 = atomicAdd(&rk[b3], 1);
                int p0 = bbase[b0] + r0, p1 = bbase[b1] + r1;
                int p2 = bbase[b2] + r2, p3 = bbase[b3] + r3;
                if (p0 < CAP) bdata[(size_t)b0 * CAP + p0] = ((d4.x & 31) << 16) | s4.x;
                if (p1 < CAP) bdata[(size_t)b1 * CAP + p1] = ((d4.y & 31) << 16) | s4.y;
                if (p2 < CAP) bdata[(size_t)b2 * CAP + p2] = ((d4.z & 31) << 16) | s4.z;
                if (p3 < CAP) bdata[(size_t)b3 * CAP + p3] = ((d4.w & 31) << 16) | s4.w;
            }
            __syncthreads();
        }
    } else {
        float (*sA)[TK + 1] = (float (*)[TK + 1])smem;            // [128][65]
        float (*sW)[F]      = (float (*)[F])(smem + 128 * (TK + 1) * 4);
        int rg = tid >> 4, cg4 = tid & 15;
        int ntasks = 2 * ((n + TM - 1) / TM);
        int pblk = gsz - nscat;
        for (int t = bid - nscat; t < ntasks; t += pblk) {
            int ty = t & 1;
            int cnt = tcnt[ty];
            int base = (t >> 1) * TM;
            if (base >= cnt) continue;                   // uniform per block
            const int*   list = ty ? list1 : list0;
            const float* A    = ty ? d_sim : m_sim;
            const float* W    = ty ? W_d   : W_m;
            int snode[4];
            #pragma unroll
            for (int j = 0; j < 4; j++) {
                int li = base + ((tid + BLK * j) >> 4);
                if (li >= cnt) li = cnt - 1;
                snode[j] = list[li];
            }
            float acc[4][4] = {};
            for (int kc = 0; kc < 256; kc += TK) {
                __syncthreads();
                #pragma unroll
                for (int j = 0; j < 4; j++) {
                    int idx = tid + BLK * j;
                    int r = idx >> 4, f4 = idx & 15;
                    float4 v = *(const float4*)(A + (size_t)snode[j] * 256 + kc + f4 * 4);
                    sA[r][f4 * 4 + 0] = v.x;
                    sA[r][f4 * 4 + 1] = v.y;
                    sA[r][f4 * 4 + 2] = v.z;
                    sA[r][f4 * 4 + 3] = v.w;
                }
                #pragma unroll
                for (int j = 0; j < 2; j++) {
                    int idx = tid + BLK * j;
                    int k = idx >> 4, f4 = idx & 15;
                    *(float4*)&sW[k][f4 * 4] =
                        *(const float4*)(W + (size_t)(kc + k) * F + f4 * 4);
                }
                __syncthreads();
                #pragma unroll 4
                for (int k = 0; k < TK; k++) {
                    float4 wv = *(const float4*)&sW[k][cg4 * 4];
                    float a[4];
                    #pragma unroll
                    for (int i = 0; i < 4; i++) a[i] = sA[rg * 4 + i][k];
                    #pragma unroll
                    for (int i = 0; i < 4; i++) {
                        acc[i][0] = fmaf(a[i], wv.x, acc[i][0]);
                        acc[i][1] = fmaf(a[i], wv.y, acc[i][1]);
                        acc[i][2] = fmaf(a[i], wv.z, acc[i][2]);
                        acc[i][3] = fmaf(a[i], wv.w, acc[i][3]);
                    }
                }
            }
            __syncthreads();
            #pragma unroll
            for (int i = 0; i < 4; i++) {
                int li = base + rg * 4 + i;
                if (li < cnt) {
                    int node = list[li];
                    float4 v = {acc[i][0], acc[i][1], acc[i][2], acc[i][3]};
                    *(float4*)(z + (size_t)node * F + cg4 * 4) = v;
                }
            }
        }
    }
    __threadfence();
    gg.sync();

    // ---------------- P3: attention (R5-proven body, grid-strided) ----------------
    {
        unsigned short* ssrc = (unsigned short*)smem;      // [1280]
        int* cnt  = (int*)(smem + 2560);                   // [32]
        int* excl = cnt + 32;                              // [32]
        int* cur  = excl + 32;                             // [32]
        int lane = tid & 63;
        int wv = tid >> 6;
        int g = lane >> 4, r = lane & 15;
        for (int b = bid; b < nbuk; b += gsz) {
            __syncthreads();                               // guard LDS reuse
            int dbase = b << BSH;
            const int* __restrict__ bd = bdata + (size_t)b * CAP;
            int len = min(bcount[b], CAP);
            if (tid < 32) { cnt[tid] = 0; cur[tid] = 0; }
            __syncthreads();
            for (int i = tid; i < len; i += BLK)
                atomicAdd(&cnt[bd[i] >> 16], 1);
            __syncthreads();
            if (tid < 32) {
                int v = cnt[tid];
                int s = v;
                #pragma unroll
                for (int off = 1; off < 32; off <<= 1) {
                    int t = __shfl_up(s, off, 32);
                    if (tid >= off) s += t;
                }
                excl[tid] = s - v;
            }
            __syncthreads();
            for (int i = tid; i < len; i += BLK) {
                int v = bd[i];
                int d5 = v >> 16;
                int rr = atomicAdd(&cur[d5], 1);
                int pos = excl[d5] + rr;
                if (pos < HCAP) ssrc[pos] = (unsigned short)(v & 0xFFFF);
            }
            __syncthreads();
            for (int k = 0; k < 4; k++) {
                int d5 = wv + 8 * k;
                int node = dbase + d5;
                if (node >= n) continue;
                int lbeg = excl[d5];
                int lcnt = min(cnt[d5], max(0, HCAP - lbeg));
                float4 zd = ((const float4*)(z + (size_t)node * F))[r];
                float m = -3.402823466e38f, l = 0.f;
                float4 acc = {0.f, 0.f, 0.f, 0.f};
                for (int j = 0; j < lcnt; j += 4) {
                    int jj = j + g;
                    int s = ssrc[lbeg + min(jj, lcnt - 1)];
                    float4 zc = ((const float4*)(z + (size_t)s * F))[r];
                    float p = fmaf(zc.x, zd.x, fmaf(zc.y, zd.y, fmaf(zc.z, zd.z, zc.w * zd.w)));
                    p += __shfl_xor(p, 1, 64);
                    p += __shfl_xor(p, 2, 64);
                    p += __shfl_xor(p, 4, 64);
                    p += __shfl_xor(p, 8, 64);
                    float e = (p > 0.f) ? p : 0.2f * p;
                    if (jj >= lcnt) e = -INFINITY;
                    float t = __expf(-fabsf(e - m));
                    bool gt = (e > m);
                    float sc = gt ? t : 1.f;
                    float w  = gt ? 1.f : t;
                    m = gt ? e : m;
                    l = fmaf(l, sc, w);
                    acc.x = fmaf(acc.x, sc, w * zc.x);
                    acc.y = fmaf(acc.y, sc, w * zc.y);
                    acc.z = fmaf(acc.z, sc, w * zc.z);
                    acc.w = fmaf(acc.w, sc, w * zc.w);
                }
                #pragma unroll
                for (int off = 16; off <= 32; off <<= 1) {
                    float om = __shfl_xor(m, off, 64);
                    float ol = __shfl_xor(l, off, 64);
                    float4 oa;
                    oa.x = __shfl_xor(acc.x, off, 64);
                    oa.y = __shfl_xor(acc.y, off, 64);
                    oa.z = __shfl_xor(acc.z, off, 64);
                    oa.w = __shfl_xor(acc.w, off, 64);
                    float t = __expf(-fabsf(m - om));
                    bool gt = (om > m);
                    float sc = gt ? t : 1.f;
                    float so = gt ? 1.f : t;
                    m = gt ? om : m;
                    l = fmaf(l, sc, ol * so);
                    acc.x = fmaf(acc.x, sc, oa.x * so);
                    acc.y = fmaf(acc.y, sc, oa.y * so);
                    acc.z = fmaf(acc.z, sc, oa.z * so);
                    acc.w = fmaf(acc.w, sc, oa.w * so);
                }
                float inv = 1.f / fmaxf(l, 1e-16f);
                float4 o;
                o.x = acc.x * inv; o.y = acc.y * inv; o.z = acc.z * inv; o.w = acc.w * inv;
                o.x = (o.x > 0.f) ? o.x : (__expf(o.x) - 1.f);
                o.y = (o.y > 0.f) ? o.y : (__expf(o.y) - 1.f);
                o.z = (o.z > 0.f) ? o.z : (__expf(o.z) - 1.f);
                o.w = (o.w > 0.f) ? o.w : (__expf(o.w) - 1.f);
                if (g == 0) ((float4*)(out + (size_t)node * F))[r] = o;
            }
        }
    }
}

// ---------------------------------------------------------------------------
// Fallback: R5-proven 4-dispatch pipeline (verbatim)
// ---------------------------------------------------------------------------
__global__ void classify_kernel(const int* __restrict__ node_type, int* __restrict__ tcnt,
                                int* __restrict__ list0, int* __restrict__ list1, int n) {
    int i = blockIdx.x * 256 + threadIdx.x;
    if (i < n) {
        int lane = threadIdx.x & 63;
        int t = node_type[i];
        unsigned long long b1 = __ballot(t == 1);
        unsigned long long ba = __ballot(1);
        unsigned long long mlt = (1ull << lane) - 1ull;
        int r1 = __popcll(b1 & mlt);
        int r0 = __popcll(ba & ~b1 & mlt);
        int base0, base1;
        if (lane == 0) {
            base1 = atomicAdd(&tcnt[1], __popcll(b1));
            base0 = atomicAdd(&tcnt[0], __popcll(ba & ~b1));
        }
        base0 = __shfl(base0, 0, 64);
        base1 = __shfl(base1, 0, 64);
        if (t == 1) list1[base1 + r1] = i;
        else        list0[base0 + r0] = i;
    }
}

__global__ __launch_bounds__(256, 2)
void proj_scatter(const float* __restrict__ d_sim, const float* __restrict__ m_sim,
                  const float* __restrict__ W_d, const float* __restrict__ W_m,
                  const int* __restrict__ tcnt, const int* __restrict__ list0,
                  const int* __restrict__ list1, float* __restrict__ z,
                  const int* __restrict__ dst, const int* __restrict__ src,
                  int* __restrict__ bucket_count, int* __restrict__ bucket_data,
                  int e, int nbuk, int nsort) {
    __shared__ __align__(16) char smem[PROJ_LDS];
    int bid = blockIdx.x;

    if (bid < nsort) {
        int* hist  = (int*)smem;
        int* bbase = hist + 2048;
        int* rk    = bbase + 2048;
        for (int i = threadIdx.x; i < nbuk; i += 256) { hist[i] = 0; rk[i] = 0; }
        __syncthreads();
        int beg = bid * CHUNK, end = min(e, beg + CHUNK);
        for (int i = beg + (int)threadIdx.x * 4; i < end; i += 1024) {
            int4 d4 = *(const int4*)(dst + i);
            atomicAdd(&hist[d4.x >> BSH], 1);
            atomicAdd(&hist[d4.y >> BSH], 1);
            atomicAdd(&hist[d4.z >> BSH], 1);
            atomicAdd(&hist[d4.w >> BSH], 1);
        }
        __syncthreads();
        for (int i = threadIdx.x; i < nbuk; i += 256)
            bbase[i] = hist[i] ? atomicAdd(&bucket_count[i], hist[i]) : 0;
        __syncthreads();
        for (int i = beg + (int)threadIdx.x * 4; i < end; i += 1024) {
            int4 d4 = *(const int4*)(dst + i);
            int4 s4 = *(const int4*)(src + i);
            int b0 = d4.x >> BSH, b1 = d4.y >> BSH, b2 = d4.z >> BSH, b3 = d4.w >> BSH;
            int r0 = atomicAdd(&rk[b0], 1);
            int r1 = atomicAdd(&rk[b1], 1);
            int r2 = atomicAdd(&rk[b2], 1);
            int r3 = atomicAdd(&rk[b3], 1);
            int p0 = bbase[b0] + r0, p1 = bbase[b1] + r1;
            int p2 = bbase[b2] + r2, p3 = bbase[b3] + r3;
            if (p0 < CAP) bucket_data[(size_t)b0 * CAP + p0] = ((d4.x & 31) << 16) | s4.x;
            if (p1 < CAP) bucket_data[(size_t)b1 * CAP + p1] = ((d4.y & 31) << 16) | s4.y;
            if (p2 < CAP) bucket_data[(size_t)b2 * CAP + p2] = ((d4.z & 31) << 16) | s4.z;
            if (p3 < CAP) bucket_data[(size_t)b3 * CAP + p3] = ((d4.w & 31) << 16) | s4.w;
        }
        return;
    }

    int pb = bid - nsort;
    int ty = pb & 1;
    int cnt = tcnt[ty];
    int base = (pb >> 1) * TM;
    if (base >= cnt) return;
    const int*   list = ty ? list1 : list0;
    const float* A    = ty ? d_sim : m_sim;
    const float* W    = ty ? W_d   : W_m;

    float (*sA)[TK + 1] = (float (*)[TK + 1])smem;
    float (*sW)[F]      = (float (*)[F])(smem + 128 * (TK + 1) * 4);

    int rg = threadIdx.x >> 4;
    int cg = threadIdx.x & 15;

    int srow_node[8];
    #pragma unroll
    for (int j = 0; j < 8; j++) {
        int idx = (int)threadIdx.x + 256 * j;
        int li = base + (idx >> 4);
        if (li >= cnt) li = cnt - 1;
        srow_node[j] = list[li];
    }

    float acc[8][4] = {};
    for (int kc = 0; kc < 256; kc += TK) {
        __syncthreads();
        #pragma unroll
        for (int j = 0; j < 8; j++) {
            int idx = (int)threadIdx.x + 256 * j;
            int r = idx >> 4, f4 = idx & 15;
            float4 v = *(const float4*)(A + (size_t)srow_node[j] * 256 + kc + f4 * 4);
            sA[r][f4 * 4 + 0] = v.x;
            sA[r][f4 * 4 + 1] = v.y;
            sA[r][f4 * 4 + 2] = v.z;
            sA[r][f4 * 4 + 3] = v.w;
        }
        #pragma unroll
        for (int j = 0; j < 4; j++) {
            int idx = (int)threadIdx.x + 256 * j;
            int k = idx >> 4, f4 = idx & 15;
            float4 v = *(const float4*)(W + (size_t)(kc + k) * F + f4 * 4);
            *(float4*)&sW[k][f4 * 4] = v;
        }
        __syncthreads();
        #pragma unroll 4
        for (int k = 0; k < TK; k++) {
            float4 wv = *(const float4*)&sW[k][cg * 4];
            float a[8];
            #pragma unroll
            for (int i = 0; i < 8; i++) a[i] = sA[rg * 8 + i][k];
            #pragma unroll
            for (int i = 0; i < 8; i++) {
                acc[i][0] = fmaf(a[i], wv.x, acc[i][0]);
                acc[i][1] = fmaf(a[i], wv.y, acc[i][1]);
                acc[i][2] = fmaf(a[i], wv.z, acc[i][2]);
                acc[i][3] = fmaf(a[i], wv.w, acc[i][3]);
            }
        }
    }
    #pragma unroll
    for (int i = 0; i < 8; i++) {
        int li = base + rg * 8 + i;
        if (li < cnt) {
            int node = list[li];
            float4 v = {acc[i][0], acc[i][1], acc[i][2], acc[i][3]};
            *(float4*)(z + (size_t)node * F + cg * 4) = v;
        }
    }
}

__global__ __launch_bounds__(512)
void attn_fused(const float* __restrict__ z, const int* __restrict__ bucket_count,
                const int* __restrict__ bucket_data, float* __restrict__ out, int n) {
    __shared__ unsigned short ssrc[HCAP];
    __shared__ int cnt[32], excl[32], cur[32];
    int b = blockIdx.x;
    int dbase = b << BSH;
    const int* __restrict__ bd = bucket_data + (size_t)b * CAP;
    int len = min(bucket_count[b], CAP);
    int tid = threadIdx.x;

    if (tid < 32) { cnt[tid] = 0; cur[tid] = 0; }
    __syncthreads();
    for (int i = tid; i < len; i += 512)
        atomicAdd(&cnt[bd[i] >> 16], 1);
    __syncthreads();
    if (tid < 32) {
        int v = cnt[tid];
        int s = v;
        #pragma unroll
        for (int off = 1; off < 32; off <<= 1) {
            int t = __shfl_up(s, off, 32);
            if (tid >= off) s += t;
        }
        excl[tid] = s - v;
    }
    __syncthreads();
    for (int i = tid; i < len; i += 512) {
        int v = bd[i];
        int d5 = v >> 16;
        int r = atomicAdd(&cur[d5], 1);
        int pos = excl[d5] + r;
        if (pos < HCAP) ssrc[pos] = (unsigned short)(v & 0xFFFF);
    }
    __syncthreads();

    int lane = tid & 63;
    int wv = tid >> 6;
    int g = lane >> 4, r = lane & 15;
    for (int k = 0; k < 4; k++) {
        int d5 = wv + 8 * k;
        int node = dbase + d5;
        if (node >= n) continue;
        int lbeg = excl[d5];
        int lcnt = min(cnt[d5], max(0, HCAP - lbeg));
        float4 zd = ((const float4*)(z + (size_t)node * F))[r];
        float m = -3.402823466e38f, l = 0.f;
        float4 acc = {0.f, 0.f, 0.f, 0.f};
        for (int j = 0; j < lcnt; j += 4) {
            int jj = j + g;
            int s = ssrc[lbeg + min(jj, lcnt - 1)];
            float4 zc = ((const float4*)(z + (size_t)s * F))[r];
            float p = fmaf(zc.x, zd.x, fmaf(zc.y, zd.y, fmaf(zc.z, zd.z, zc.w * zd.w)));
            p += __shfl_xor(p, 1, 64);
            p += __shfl_xor(p, 2, 64);
            p += __shfl_xor(p, 4, 64);
            p += __shfl_xor(p, 8, 64);
            float e = (p > 0.f) ? p : 0.2f * p;
            if (jj >= lcnt) e = -INFINITY;
            float t = __expf(-fabsf(e - m));
            bool gt = (e > m);
            float sc = gt ? t : 1.f;
            float w  = gt ? 1.f : t;
            m = gt ? e : m;
            l = fmaf(l, sc, w);
            acc.x = fmaf(acc.x, sc, w * zc.x);
            acc.y = fmaf(acc.y, sc, w * zc.y);
            acc.z = fmaf(acc.z, sc, w * zc.z);
            acc.w = fmaf(acc.w, sc, w * zc.w);
        }
        #pragma unroll
        for (int off = 16; off <= 32; off <<= 1) {
            float om = __shfl_xor(m, off, 64);
            float ol = __shfl_xor(l, off, 64);
            float4 oa;
            oa.x = __shfl_xor(acc.x, off, 64);
            oa.y = __shfl_xor(acc.y, off, 64);
            oa.z = __shfl_xor(acc.z, off, 64);
            oa.w = __shfl_xor(acc.w, off, 64);
            float t = __expf(-fabsf(m - om));
            bool gt = (om > m);
            float sc = gt ? t : 1.f;
            float so = gt ? 1.f : t;
            m = gt ? om : m;
            l = fmaf(l, sc, ol * so);
            acc.x = fmaf(acc.x, sc, oa.x * so);
            acc.y = fmaf(acc.y, sc, oa.y * so);
            acc.z = fmaf(acc.z, sc, oa.z * so);
            acc.w = fmaf(acc.w, sc, oa.w * so);
        }
        float inv = 1.f / fmaxf(l, 1e-16f);
        float4 o;
        o.x = acc.x * inv; o.y = acc.y * inv; o.z = acc.z * inv; o.w = acc.w * inv;
        o.x = (o.x > 0.f) ? o.x : (__expf(o.x) - 1.f);
        o.y = (o.y > 0.f) ? o.y : (__expf(o.y) - 1.f);
        o.z = (o.z > 0.f) ? o.z : (__expf(o.z) - 1.f);
        o.w = (o.w > 0.f) ? o.w : (__expf(o.w) - 1.f);
        if (g == 0) ((float4*)(out + (size_t)node * F))[r] = o;
    }
}

extern "C" void kernel_launch(void* const* d_in, const int* in_sizes, int n_in,
                              void* d_out, int out_size, void* d_ws, size_t ws_size,
                              hipStream_t stream) {
    const float* d_sim     = (const float*)d_in[0];
    const float* m_sim     = (const float*)d_in[1];
    const float* W_d       = (const float*)d_in[2];
    const float* W_m       = (const float*)d_in[3];
    const int*   node_type = (const int*)d_in[4];
    const int*   src       = (const int*)d_in[5];
    const int*   dst       = (const int*)d_in[6];
    float* out = (float*)d_out;

    int N = in_sizes[4];
    int E = in_sizes[5];
    int NBUK = (N + 31) >> BSH;                 // 1563 for N=50000 (<=2048 assumed)
    int NCHUNK = (E + CHUNK - 1) / CHUNK;       // 306

    char* ws = (char*)d_ws;
    int*   tcnt   = (int*)ws;                         // 2
    int*   bcount = tcnt + 2;                         // 2048
    int    head   = (2 + 2048 + 3) & ~3;
    float* z      = (float*)(ws + (size_t)head * 4);  // N*F
    int*   list0  = (int*)(z + (size_t)N * F);        // N
    int*   list1  = list0 + N;                        // N
    int*   bdata  = list1 + N;                        // NBUK*CAP

    // ---- cooperative capability probe (cached across calls) ----
    static int coop_grid = 0;                   // 0=unknown, >0=grid size, -1=off
    if (coop_grid == 0) {
        int dev = 0;
        (void)hipGetDevice(&dev);
        int coop = 0, ncu = 0, nb = 0;
        (void)hipDeviceGetAttribute(&coop, hipDeviceAttributeCooperativeLaunch, dev);
        (void)hipDeviceGetAttribute(&ncu, hipDeviceAttributeMultiprocessorCount, dev);
        hipError_t oe = hipOccupancyMaxActiveBlocksPerMultiprocessor(
            &nb, (const void*)mega, BLK, (size_t)SMEM_SZ);
        if (coop && ncu > 0 && oe == hipSuccess && nb > 0) {
            long g = (long)nb * ncu;
            coop_grid = (int)(g > 2048 ? 2048 : g);
        } else {
            coop_grid = -1;
        }
    }

    if (coop_grid > 0) {
        int gsz = coop_grid;
        int nscat = gsz / 3; if (nscat < 1) nscat = 1; if (nscat >= gsz) nscat = gsz - 1;
        void* args[] = {&d_sim, &m_sim, &W_d, &W_m, &node_type, &src, &dst, &out,
                        &tcnt, &bcount, &list0, &list1, &z, &bdata,
                        &N, &E, &NBUK, &NCHUNK, &nscat};
        hipError_t e = hipLaunchCooperativeKernel((const void*)mega, dim3(gsz), dim3(BLK),
                                                  args, SMEM_SZ, stream);
        if (e == hipSuccess) return;
        // launch rejected with nothing enqueued (R4 evidence) -> retry smaller once
        int gsz2 = gsz > 256 ? 256 : gsz / 2;
        if (gsz2 >= 8) {
            int nscat2 = gsz2 / 3; if (nscat2 < 1) nscat2 = 1;
            void* args2[] = {&d_sim, &m_sim, &W_d, &W_m, &node_type, &src, &dst, &out,
                             &tcnt, &bcount, &list0, &list1, &z, &bdata,
                             &N, &E, &NBUK, &NCHUNK, &nscat2};
            e = hipLaunchCooperativeKernel((const void*)mega, dim3(gsz2), dim3(BLK),
                                           args2, SMEM_SZ, stream);
            if (e == hipSuccess) { coop_grid = gsz2; return; }
        }
        coop_grid = -1;                         // fall through to proven pipeline
    }

    // ---- fallback: R5-proven 4-dispatch pipeline ----
    hipMemsetAsync(tcnt, 0, (size_t)(2 + 2048) * sizeof(int), stream);
    dim3 blk(256);
    classify_kernel<<<dim3((N + 255) / 256), blk, 0, stream>>>(node_type, tcnt, list0, list1, N);
    int nsort = (E + CHUNK - 1) / CHUNK;
    int pgrid = 2 * ((N + TM - 1) / TM);
    proj_scatter<<<dim3(nsort + pgrid), blk, 0, stream>>>(d_sim, m_sim, W_d, W_m,
                                                          tcnt, list0, list1, z,
                                                          dst, src, bcount, bdata,
                                                          E, NBUK, nsort);
    attn_fused<<<dim3(NBUK), dim3(512), 0, stream>>>(z, bcount, bdata, out, N);
}

// Round 7
// 237.152 us; speedup vs baseline: 2.2812x; 2.2812x over previous
//
#include <hip/hip_runtime.h>
#include <hip/hip_fp16.h>
#include <math.h>

// Pipeline (4 launches) — R5-proven structure + fp16 z (R7):
//  memset:   zero tcnt + bucket_count
//  classify: split node ids by type into list0/list1 (wave-aggregated atomics)
//  proj_scatter (FUSED): one grid, branch on blockIdx.
//     - blocks [0, nsort): bucket_scatter at 256 thr/block, 4 edges/thread via
//       int4 loads (chunk=4096). Edges into per-bucket slabs bdata[b*CAP..]
//       (bucket = dst>>5, 32 dsts -> one attn block each). R2 lesson: scatter
//       is latency-bound -> maximize blocks+ILP.
//     - blocks [nsort, nsort+PGRID): per-type register-tiled GEMM
//       z[list[i]] = A[list[i]] @ W, output stored FP16 (halves gather bytes).
//  attn_fused: one 512-thr block per 32-dst bucket. Two cheap LDS passes build
//     per-dst CSR (ushort srcs), then 8 waves x 4 dsts online-softmax with the
//     R1-measured-best gather (16 lanes/edge, 4-shfl reduce). z rows are fp16:
//     128 B/row -> raw gather demand 320->160 MB and z (6.4 MB) fits in L2/L3.
//     R6 lesson: grid.sync costs ~130us on MI355X -> stay multi-dispatch.
// Assumes N <= 65536 (src packed into low 16 bits of bdata; NBUK <= 2048).

#define F 64
#define TM 128
#define TK 64
#define BSH 5                    // bucket = dst >> 5 (32 dsts per bucket)
#define CHUNK 4096               // edges per scatter block (mult of 4)
#define CAP 1280                 // slab capacity per bucket (mean 800, +17 sigma)
#define HCAP 1280                // per-bucket LDS list capacity

#define PROJ_LDS (128 * (TK + 1) * 4 + TK * F * 4)   // 33280 + 16384 = 49664 B

__global__ void classify_kernel(const int* __restrict__ node_type, int* __restrict__ tcnt,
                                int* __restrict__ list0, int* __restrict__ list1, int n) {
    int i = blockIdx.x * 256 + threadIdx.x;
    if (i < n) {
        int lane = threadIdx.x & 63;
        int t = node_type[i];
        unsigned long long b1 = __ballot(t == 1);
        unsigned long long ba = __ballot(1);
        unsigned long long mlt = (1ull << lane) - 1ull;
        int r1 = __popcll(b1 & mlt);
        int r0 = __popcll(ba & ~b1 & mlt);
        int base0, base1;
        if (lane == 0) {
            base1 = atomicAdd(&tcnt[1], __popcll(b1));
            base0 = atomicAdd(&tcnt[0], __popcll(ba & ~b1));
        }
        base0 = __shfl(base0, 0, 64);
        base1 = __shfl(base1, 0, 64);
        if (t == 1) list1[base1 + r1] = i;
        else        list0[base0 + r0] = i;
    }
}

__global__ __launch_bounds__(256, 2)
void proj_scatter(const float* __restrict__ d_sim, const float* __restrict__ m_sim,
                  const float* __restrict__ W_d, const float* __restrict__ W_m,
                  const int* __restrict__ tcnt, const int* __restrict__ list0,
                  const int* __restrict__ list1, unsigned short* __restrict__ zh,
                  const int* __restrict__ dst, const int* __restrict__ src,
                  int* __restrict__ bucket_count, int* __restrict__ bucket_data,
                  int e, int nbuk, int nsort) {
    __shared__ __align__(16) char smem[PROJ_LDS];    // union: proj 49664B / scatter 24576B
    int bid = blockIdx.x;

    if (bid < nsort) {
        // ---- bucket_scatter branch: 256 thr, 4 edges/thread via int4 ----
        int* hist  = (int*)smem;        // [2048]
        int* bbase = hist + 2048;       // [2048]
        int* rk    = bbase + 2048;      // [2048]
        for (int i = threadIdx.x; i < nbuk; i += 256) { hist[i] = 0; rk[i] = 0; }
        __syncthreads();
        int beg = bid * CHUNK, end = min(e, beg + CHUNK);
        for (int i = beg + (int)threadIdx.x * 4; i < end; i += 1024) {
            int4 d4 = *(const int4*)(dst + i);      // e mult of 4 assumed
            atomicAdd(&hist[d4.x >> BSH], 1);
            atomicAdd(&hist[d4.y >> BSH], 1);
            atomicAdd(&hist[d4.z >> BSH], 1);
            atomicAdd(&hist[d4.w >> BSH], 1);
        }
        __syncthreads();
        for (int i = threadIdx.x; i < nbuk; i += 256)
            bbase[i] = hist[i] ? atomicAdd(&bucket_count[i], hist[i]) : 0;
        __syncthreads();
        for (int i = beg + (int)threadIdx.x * 4; i < end; i += 1024) {
            int4 d4 = *(const int4*)(dst + i);
            int4 s4 = *(const int4*)(src + i);
            int b0 = d4.x >> BSH, b1 = d4.y >> BSH, b2 = d4.z >> BSH, b3 = d4.w >> BSH;
            int r0 = atomicAdd(&rk[b0], 1);
            int r1 = atomicAdd(&rk[b1], 1);
            int r2 = atomicAdd(&rk[b2], 1);
            int r3 = atomicAdd(&rk[b3], 1);
            int p0 = bbase[b0] + r0, p1 = bbase[b1] + r1;
            int p2 = bbase[b2] + r2, p3 = bbase[b3] + r3;
            if (p0 < CAP) bucket_data[(size_t)b0 * CAP + p0] = ((d4.x & 31) << 16) | s4.x;
            if (p1 < CAP) bucket_data[(size_t)b1 * CAP + p1] = ((d4.y & 31) << 16) | s4.y;
            if (p2 < CAP) bucket_data[(size_t)b2 * CAP + p2] = ((d4.z & 31) << 16) | s4.z;
            if (p3 < CAP) bucket_data[(size_t)b3 * CAP + p3] = ((d4.w & 31) << 16) | s4.w;
        }
        return;
    }

    // ------------------------- proj_gemm branch --------------------------
    int pb = bid - nsort;
    int ty = pb & 1;
    int cnt = tcnt[ty];
    int base = (pb >> 1) * TM;
    if (base >= cnt) return;
    const int*   list = ty ? list1 : list0;
    const float* A    = ty ? d_sim : m_sim;
    const float* W    = ty ? W_d   : W_m;

    float (*sA)[TK + 1] = (float (*)[TK + 1])smem;
    float (*sW)[F]      = (float (*)[F])(smem + 128 * (TK + 1) * 4);

    int rg = threadIdx.x >> 4;
    int cg = threadIdx.x & 15;

    int srow_node[8];
    #pragma unroll
    for (int j = 0; j < 8; j++) {
        int idx = (int)threadIdx.x + 256 * j;
        int li = base + (idx >> 4);
        if (li >= cnt) li = cnt - 1;
        srow_node[j] = list[li];
    }

    float acc[8][4] = {};
    for (int kc = 0; kc < 256; kc += TK) {
        __syncthreads();
        #pragma unroll
        for (int j = 0; j < 8; j++) {
            int idx = (int)threadIdx.x + 256 * j;
            int r = idx >> 4, f4 = idx & 15;
            float4 v = *(const float4*)(A + (size_t)srow_node[j] * 256 + kc + f4 * 4);
            sA[r][f4 * 4 + 0] = v.x;
            sA[r][f4 * 4 + 1] = v.y;
            sA[r][f4 * 4 + 2] = v.z;
            sA[r][f4 * 4 + 3] = v.w;
        }
        #pragma unroll
        for (int j = 0; j < 4; j++) {
            int idx = (int)threadIdx.x + 256 * j;
            int k = idx >> 4, f4 = idx & 15;
            float4 v = *(const float4*)(W + (size_t)(kc + k) * F + f4 * 4);
            *(float4*)&sW[k][f4 * 4] = v;
        }
        __syncthreads();
        #pragma unroll 4
        for (int k = 0; k < TK; k++) {
            float4 wv = *(const float4*)&sW[k][cg * 4];
            float a[8];
            #pragma unroll
            for (int i = 0; i < 8; i++) a[i] = sA[rg * 8 + i][k];
            #pragma unroll
            for (int i = 0; i < 8; i++) {
                acc[i][0] = fmaf(a[i], wv.x, acc[i][0]);
                acc[i][1] = fmaf(a[i], wv.y, acc[i][1]);
                acc[i][2] = fmaf(a[i], wv.z, acc[i][2]);
                acc[i][3] = fmaf(a[i], wv.w, acc[i][3]);
            }
        }
    }
    #pragma unroll
    for (int i = 0; i < 8; i++) {
        int li = base + rg * 8 + i;
        if (li < cnt) {
            int node = list[li];
            __half2 ha = __floats2half2_rn(acc[i][0], acc[i][1]);
            __half2 hb = __floats2half2_rn(acc[i][2], acc[i][3]);
            uint2 u;
            u.x = *(unsigned int*)&ha;
            u.y = *(unsigned int*)&hb;
            *(uint2*)(zh + (size_t)node * F + cg * 4) = u;   // 8B store, 16 lanes = 128B row
        }
    }
}

__global__ __launch_bounds__(512)
void attn_fused(const unsigned short* __restrict__ zh, const int* __restrict__ bucket_count,
                const int* __restrict__ bucket_data, float* __restrict__ out, int n) {
    __shared__ unsigned short ssrc[HCAP];
    __shared__ int cnt[32], excl[32], cur[32];
    int b = blockIdx.x;
    int dbase = b << BSH;
    const int* __restrict__ bd = bucket_data + (size_t)b * CAP;
    int len = min(bucket_count[b], CAP);
    int tid = threadIdx.x;

    if (tid < 32) { cnt[tid] = 0; cur[tid] = 0; }
    __syncthreads();
    // pass 1: per-dst counts (bucket holds only our 32 dsts)
    for (int i = tid; i < len; i += 512)
        atomicAdd(&cnt[bd[i] >> 16], 1);
    __syncthreads();
    if (tid < 32) {                   // 32-wide shfl exclusive scan (one wave)
        int v = cnt[tid];
        int s = v;
        #pragma unroll
        for (int off = 1; off < 32; off <<= 1) {
            int t = __shfl_up(s, off, 32);
            if (tid >= off) s += t;
        }
        excl[tid] = s - v;
    }
    __syncthreads();
    // pass 2: scatter srcs into LDS grouped by dst
    for (int i = tid; i < len; i += 512) {
        int v = bd[i];
        int d5 = v >> 16;
        int r = atomicAdd(&cur[d5], 1);
        int pos = excl[d5] + r;
        if (pos < HCAP) ssrc[pos] = (unsigned short)(v & 0xFFFF);
    }
    __syncthreads();

    // attention: wave wv handles dsts d5 = wv + 8k; 16 lanes/edge (R1-best),
    // fp16 z rows: lane r loads 8B (4 halves) of the 128B row.
    int lane = tid & 63;
    int wv = tid >> 6;
    int g = lane >> 4, r = lane & 15;
    for (int k = 0; k < 4; k++) {
        int d5 = wv + 8 * k;
        int node = dbase + d5;
        if (node >= n) continue;
        int lbeg = excl[d5];
        int lcnt = min(cnt[d5], max(0, HCAP - lbeg));
        uint2 ud = *(const uint2*)(zh + (size_t)node * F + r * 4);
        float2 d0 = __half22float2(*(const __half2*)&ud.x);
        float2 d1 = __half22float2(*(const __half2*)&ud.y);
        float4 zd = {d0.x, d0.y, d1.x, d1.y};
        float m = -3.402823466e38f, l = 0.f;
        float4 acc = {0.f, 0.f, 0.f, 0.f};
        for (int j = 0; j < lcnt; j += 4) {
            int jj = j + g;
            int s = ssrc[lbeg + min(jj, lcnt - 1)];   // LDS broadcast per group
            uint2 u = *(const uint2*)(zh + (size_t)s * F + r * 4);
            float2 f0 = __half22float2(*(const __half2*)&u.x);
            float2 f1 = __half22float2(*(const __half2*)&u.y);
            float p = fmaf(f0.x, zd.x, fmaf(f0.y, zd.y, fmaf(f1.x, zd.z, f1.y * zd.w)));
            p += __shfl_xor(p, 1, 64);
            p += __shfl_xor(p, 2, 64);
            p += __shfl_xor(p, 4, 64);
            p += __shfl_xor(p, 8, 64);
            float e = (p > 0.f) ? p : 0.2f * p;       // leaky_relu
            if (jj >= lcnt) e = -INFINITY;
            float t = __expf(-fabsf(e - m));          // single-exp online update
            bool gt = (e > m);
            float sc = gt ? t : 1.f;
            float w  = gt ? 1.f : t;
            m = gt ? e : m;
            l = fmaf(l, sc, w);
            acc.x = fmaf(acc.x, sc, w * f0.x);
            acc.y = fmaf(acc.y, sc, w * f0.y);
            acc.z = fmaf(acc.z, sc, w * f1.x);
            acc.w = fmaf(acc.w, sc, w * f1.y);
        }
        // merge the 4 groups
        #pragma unroll
        for (int off = 16; off <= 32; off <<= 1) {
            float om = __shfl_xor(m, off, 64);
            float ol = __shfl_xor(l, off, 64);
            float4 oa;
            oa.x = __shfl_xor(acc.x, off, 64);
            oa.y = __shfl_xor(acc.y, off, 64);
            oa.z = __shfl_xor(acc.z, off, 64);
            oa.w = __shfl_xor(acc.w, off, 64);
            float t = __expf(-fabsf(m - om));
            bool gt = (om > m);
            float sc = gt ? t : 1.f;
            float so = gt ? 1.f : t;
            m = gt ? om : m;
            l = fmaf(l, sc, ol * so);
            acc.x = fmaf(acc.x, sc, oa.x * so);
            acc.y = fmaf(acc.y, sc, oa.y * so);
            acc.z = fmaf(acc.z, sc, oa.z * so);
            acc.w = fmaf(acc.w, sc, oa.w * so);
        }
        float inv = 1.f / fmaxf(l, 1e-16f);
        float4 o;
        o.x = acc.x * inv; o.y = acc.y * inv; o.z = acc.z * inv; o.w = acc.w * inv;
        o.x = (o.x > 0.f) ? o.x : (__expf(o.x) - 1.f);
        o.y = (o.y > 0.f) ? o.y : (__expf(o.y) - 1.f);
        o.z = (o.z > 0.f) ? o.z : (__expf(o.z) - 1.f);
        o.w = (o.w > 0.f) ? o.w : (__expf(o.w) - 1.f);
        if (g == 0) ((float4*)(out + (size_t)node * F))[r] = o;
    }
}

extern "C" void kernel_launch(void* const* d_in, const int* in_sizes, int n_in,
                              void* d_out, int out_size, void* d_ws, size_t ws_size,
                              hipStream_t stream) {
    const float* d_sim     = (const float*)d_in[0];
    const float* m_sim     = (const float*)d_in[1];
    const float* W_d       = (const float*)d_in[2];
    const float* W_m       = (const float*)d_in[3];
    const int*   node_type = (const int*)d_in[4];
    const int*   src       = (const int*)d_in[5];
    const int*   dst       = (const int*)d_in[6];
    float* out = (float*)d_out;

    const int N = in_sizes[4];
    const int E = in_sizes[5];
    const int NBUK = (N + 31) >> BSH;           // 1563 for N=50000 (<=2048 assumed)

    char* ws = (char*)d_ws;
    int*            tcnt   = (int*)ws;                          // 2
    int*            bcount = tcnt + 2;                          // 2048
    int             head   = (2 + 2048 + 3) & ~3;               // align to 16B
    unsigned short* zh     = (unsigned short*)(ws + (size_t)head * 4);  // N*F fp16
    int*            list0  = (int*)(zh + (size_t)N * F);        // N (offset mult of 128B)
    int*            list1  = list0 + N;                         // N
    int*            bdata  = list1 + N;                         // NBUK*CAP

    hipMemsetAsync(tcnt, 0, (size_t)(2 + 2048) * sizeof(int), stream);

    dim3 blk(256);
    classify_kernel<<<dim3((N + 255) / 256), blk, 0, stream>>>(node_type, tcnt, list0, list1, N);

    int nsort = (E + CHUNK - 1) / CHUNK;        // 306 for E=1.25M
    int pgrid = 2 * ((N + TM - 1) / TM);        // 782
    proj_scatter<<<dim3(nsort + pgrid), blk, 0, stream>>>(d_sim, m_sim, W_d, W_m,
                                                          tcnt, list0, list1, zh,
                                                          dst, src, bcount, bdata,
                                                          E, NBUK, nsort);
    attn_fused<<<dim3(NBUK), dim3(512), 0, stream>>>(zh, bcount, bdata, out, N);
}